// Round 2
// baseline (52.117 us; speedup 1.0000x reference)
//
#include <hip/hip_runtime.h>
#include <math.h>

#define NS 8192
#define MS 2048
#define DD 32
#define SPLITM 32
#define CH (MS / SPLITM)   // 64 means per block

// ws layout (floats)
#define BC_OFF 0                       // M*64
#define A2_OFF (MS * 64)               // M
#define P_OFF  (A2_OFF + MS)           // SPLITM*NS
#define D_OFF  (P_OFF + SPLITM * NS)   // NS
#define MM_OFF (D_OFF + NS)            // 2 (uint bits: [min, max])

__device__ inline float fast_exp2(float x) {
#if __has_builtin(__builtin_amdgcn_exp2f)
    return __builtin_amdgcn_exp2f(x);
#else
    return exp2f(x);
#endif
}

// Precompute BC[m][0..31]=log2e*mu/sd, BC[m][32..63]=-0.5*log2e/sd,
// A2[m] = -0.5*log2e*sum(mu^2/sd) - log2(M)   <-- folds the 1/M of the mean
// into the exponent so the hot loop needs no divide.
__global__ void prep_kernel(const float* __restrict__ means,
                            const float* __restrict__ stds,
                            float* __restrict__ ws) {
    int m = blockIdx.x * blockDim.x + threadIdx.x;
    if (m == 0) {
        unsigned* mm = (unsigned*)(ws + MM_OFF);
        mm[0] = 0x7f7fffffu;  // min slot init = FLT_MAX (bits)
        mm[1] = 0u;           // max slot init = 0.0f
    }
    if (m >= MS) return;
    const float L2E   = 1.4426950408889634f;
    const float LOG2M = 11.0f;  // log2(2048)
    float a = 0.0f;
    float* bc = ws + BC_OFF + (size_t)m * 64;
#pragma unroll
    for (int d = 0; d < DD; ++d) {
        float mu  = means[m * DD + d];
        float sd  = stds[m * DD + d];
        float inv = 1.0f / sd;
        bc[d]      = L2E * mu * inv;
        bc[32 + d] = -0.5f * L2E * inv;
        a += mu * mu * inv;
    }
    ws[A2_OFF + m] = -0.5f * L2E * a - LOG2M;
}

// Main: lanes index samples n; m-loop is wave-uniform so BC/A2 loads scalarize.
__global__ __launch_bounds__(256) void kde_main(const float* __restrict__ samples,
                                                const float* __restrict__ ws,
                                                float* __restrict__ partial) {
    const int n  = blockIdx.y * 256 + threadIdx.x;
    const int m0 = blockIdx.x * CH;

    float s[DD], s2[DD];
    const float4* sp = (const float4*)(samples + (size_t)n * DD);
#pragma unroll
    for (int i = 0; i < DD / 4; ++i) {
        float4 v = sp[i];
        s[4 * i + 0] = v.x; s2[4 * i + 0] = v.x * v.x;
        s[4 * i + 1] = v.y; s2[4 * i + 1] = v.y * v.y;
        s[4 * i + 2] = v.z; s2[4 * i + 2] = v.z * v.z;
        s[4 * i + 3] = v.w; s2[4 * i + 3] = v.w * v.w;
    }

    const float* __restrict__ BC = ws + BC_OFF;
    const float* __restrict__ A2 = ws + A2_OFF;

    float tot = 0.0f;
    for (int m = m0; m < m0 + CH; ++m) {
        const float* r = BC + (size_t)m * 64;
        float aB0 = 0.f, aB1 = 0.f, aC0 = 0.f, aC1 = 0.f;
#pragma unroll
        for (int d = 0; d < DD; d += 2) {
            aB0 = fmaf(r[d],          s[d],      aB0);
            aB1 = fmaf(r[d + 1],      s[d + 1],  aB1);
            aC0 = fmaf(r[32 + d],     s2[d],     aC0);
            aC1 = fmaf(r[32 + d + 1], s2[d + 1], aC1);
        }
        float lp = A2[m] + ((aB0 + aB1) + (aC0 + aC1));
        tot += fast_exp2(lp);
    }
    partial[(size_t)blockIdx.x * NS + n] = tot;
}

// Sum partials -> dist[n]; block-reduce min/max -> atomics on uint bits (dist >= 0).
__global__ __launch_bounds__(256) void reduce_kernel(const float* __restrict__ partial,
                                                     float* __restrict__ dist,
                                                     unsigned* __restrict__ mm) {
    const int n = blockIdx.x * 256 + threadIdx.x;
    float v = 0.0f;
#pragma unroll
    for (int j = 0; j < SPLITM; ++j) v += partial[(size_t)j * NS + n];
    dist[n] = v;

    float mn = v, mx = v;
#pragma unroll
    for (int o = 1; o < 64; o <<= 1) {
        mn = fminf(mn, __shfl_xor(mn, o));
        mx = fmaxf(mx, __shfl_xor(mx, o));
    }
    __shared__ float smn[4], smx[4];
    const int wid = threadIdx.x >> 6, lane = threadIdx.x & 63;
    if (lane == 0) { smn[wid] = mn; smx[wid] = mx; }
    __syncthreads();
    if (threadIdx.x == 0) {
#pragma unroll
        for (int j = 1; j < 4; ++j) {
            mn = fminf(mn, smn[j]);
            mx = fmaxf(mx, smx[j]);
        }
        atomicMin(mm + 0, __float_as_uint(mn));
        atomicMax(mm + 1, __float_as_uint(mx));
    }
}

__global__ __launch_bounds__(256) void finalize_kernel(const float* __restrict__ dist,
                                                       const unsigned* __restrict__ mm,
                                                       float* __restrict__ out) {
    const int n = blockIdx.x * 256 + threadIdx.x;
    const float mn = __uint_as_float(mm[0]);
    const float mx = __uint_as_float(mm[1]);
    out[n] = mx + mn - dist[n];
}

extern "C" void kernel_launch(void* const* d_in, const int* in_sizes, int n_in,
                              void* d_out, int out_size, void* d_ws, size_t ws_size,
                              hipStream_t stream) {
    const float* samples = (const float*)d_in[0];
    const float* means   = (const float*)d_in[1];
    const float* stds    = (const float*)d_in[2];
    float* ws  = (float*)d_ws;
    float* out = (float*)d_out;

    prep_kernel<<<dim3((MS + 255) / 256), 256, 0, stream>>>(means, stds, ws);
    kde_main<<<dim3(SPLITM, NS / 256), 256, 0, stream>>>(samples, ws, ws + P_OFF);
    reduce_kernel<<<dim3(NS / 256), 256, 0, stream>>>(ws + P_OFF, ws + D_OFF,
                                                      (unsigned*)(ws + MM_OFF));
    finalize_kernel<<<dim3(NS / 256), 256, 0, stream>>>(ws + D_OFF, (unsigned*)(ws + MM_OFF),
                                                        out);
}

// Round 3
// 40.965 us; speedup vs baseline: 1.2722x; 1.2722x over previous
//
#include <hip/hip_runtime.h>

#define NS 8192
#define MS 2048
#define DD 32
#define MSPLIT 32

typedef __attribute__((ext_vector_type(8))) short bf16x8;
typedef __attribute__((ext_vector_type(4))) float f32x4;
typedef unsigned short u16;

// ---- ws byte offsets ----
#define WH_OFF   (0)                        // [M][64] bf16 hi  (256 KB)
#define WL_OFF   (256*1024)                 // [M][64] bf16 lo  (256 KB)
#define XH_OFF   (512*1024)                 // [N][32] s  hi    (512 KB)
#define XL_OFF   (1024*1024)                // [N][32] s  lo
#define QH_OFF   (1536*1024)                // [N][32] s^2 hi
#define QL_OFF   (2048*1024)                // [N][32] s^2 lo
#define A2_OFF   (2560*1024)                // [M] f32 (8 KB)
#define PART_OFF (A2_OFF + 8*1024)          // [MSPLIT][N] f32 (1 MB)
#define DIST_OFF (PART_OFF + MSPLIT*NS*4)   // [N] f32
#define MM_OFF   (DIST_OFF + NS*4)          // 2 u32 (min,max bits)
#define CNT_OFF  (MM_OFF + 8)               // 1 u32

__device__ inline float fast_exp2(float x) {
#if __has_builtin(__builtin_amdgcn_exp2f)
    return __builtin_amdgcn_exp2f(x);
#else
    return exp2f(x);
#endif
}

__device__ inline u16 f2bf(float x) {  // round-to-nearest-even bf16
    unsigned u = __float_as_uint(x);
    return (u16)((u + 0x7fffu + ((u >> 16) & 1u)) >> 16);
}
__device__ inline float bf2f(u16 h) { return __uint_as_float(((unsigned)h) << 16); }

// blocks 0..7: per-m coefficients W=[B;C] (hi/lo bf16, [M][64] transposed) + A2.
// blocks 8..263: per-sample split of s and s^2 into hi/lo bf16 [N][32].
__global__ __launch_bounds__(256) void prep_kernel(const float* __restrict__ samples,
                                                   const float* __restrict__ means,
                                                   const float* __restrict__ stds,
                                                   unsigned char* __restrict__ ws) {
    const int tid = threadIdx.x, bid = blockIdx.x;
    if (bid == 0 && tid == 0) {
        unsigned* mm = (unsigned*)(ws + MM_OFF);
        mm[0] = 0x7f7fffffu;  // FLT_MAX bits
        mm[1] = 0u;
        *(unsigned*)(ws + CNT_OFF) = 0u;
    }
    if (bid < 8) {
        const int m = bid * 256 + tid;
        u16* WH = (u16*)(ws + WH_OFF);
        u16* WL = (u16*)(ws + WL_OFF);
        float* A2 = (float*)(ws + A2_OFF);
        const float L2E = 1.4426950408889634f;
        float a = 0.f;
#pragma unroll
        for (int d = 0; d < DD; ++d) {
            float mu  = means[m * DD + d];
            float sd  = stds[m * DD + d];
            float inv = 1.0f / sd;
            float B = L2E * mu * inv;
            float C = -0.5f * L2E * inv;
            a += mu * mu * inv;
            u16 h = f2bf(B);
            WH[m * 64 + d] = h;
            WL[m * 64 + d] = f2bf(B - bf2f(h));
            h = f2bf(C);
            WH[m * 64 + 32 + d] = h;
            WL[m * 64 + 32 + d] = f2bf(C - bf2f(h));
        }
        A2[m] = -0.5f * L2E * a - 11.0f;  // fold mean's 1/2048 into exponent
    } else {
        const int idx = (bid - 8) * 256 + tid;  // < NS*DD/4
        float4 v = ((const float4*)samples)[idx];
        float xs[4] = {v.x, v.y, v.z, v.w};
        ushort4 hx, lx, hq, lq;
        u16* ph = (u16*)&hx; u16* pl = (u16*)&lx;
        u16* qh = (u16*)&hq; u16* ql = (u16*)&lq;
#pragma unroll
        for (int j = 0; j < 4; ++j) {
            float x = xs[j];
            u16 h = f2bf(x);
            ph[j] = h;
            pl[j] = f2bf(x - bf2f(h));
            float q = x * x;
            u16 hh = f2bf(q);
            qh[j] = hh;
            ql[j] = f2bf(q - bf2f(hh));
        }
        *(ushort4*)((u16*)(ws + XH_OFF) + idx * 4) = hx;
        *(ushort4*)((u16*)(ws + XL_OFF) + idx * 4) = lx;
        *(ushort4*)((u16*)(ws + QH_OFF) + idx * 4) = hq;
        *(ushort4*)((u16*)(ws + QL_OFF) + idx * 4) = lq;
    }
}

// Each wave: 64 rows (4 n-tiles) x 64 m (4 m-tiles). 6 MFMA per 16x16 tile
// (Xh*Wh, Xh*Wl, Xl*Wh over 2 k-steps). Epilogue: exp2(acc + A2[m]) row-summed.
__global__ __launch_bounds__(256, 4) void kde_mfma(const unsigned char* __restrict__ ws,
                                                   float* __restrict__ partial) {
    const u16* XH = (const u16*)(ws + XH_OFF);
    const u16* XL = (const u16*)(ws + XL_OFF);
    const u16* QH = (const u16*)(ws + QH_OFF);
    const u16* QL = (const u16*)(ws + QL_OFF);
    const u16* WH = (const u16*)(ws + WH_OFF);
    const u16* WL = (const u16*)(ws + WL_OFF);
    const float* A2 = (const float*)(ws + A2_OFF);

    const int lane = threadIdx.x & 63, wid = threadIdx.x >> 6;
    const int r15 = lane & 15, g = lane >> 4;
    const int n_base = (blockIdx.x * 4 + wid) * 64;

    bf16x8 xh[4], xl[4], qh[4], ql[4];
#pragma unroll
    for (int nt = 0; nt < 4; ++nt) {
        const size_t off = (size_t)(n_base + nt * 16 + r15) * DD + g * 8;
        xh[nt] = *(const bf16x8*)(XH + off);
        xl[nt] = *(const bf16x8*)(XL + off);
        qh[nt] = *(const bf16x8*)(QH + off);
        ql[nt] = *(const bf16x8*)(QL + off);
    }

    f32x4 rs[4];
#pragma unroll
    for (int nt = 0; nt < 4; ++nt) rs[nt] = (f32x4){0.f, 0.f, 0.f, 0.f};

    const int m0 = blockIdx.y * 64;
#pragma unroll
    for (int it = 0; it < 4; ++it) {
        const int mrow = m0 + it * 16 + r15;
        const size_t woff = (size_t)mrow * 64 + g * 8;
        bf16x8 wh0 = *(const bf16x8*)(WH + woff);
        bf16x8 wh1 = *(const bf16x8*)(WH + woff + 32);
        bf16x8 wl0 = *(const bf16x8*)(WL + woff);
        bf16x8 wl1 = *(const bf16x8*)(WL + woff + 32);
        const float a2 = A2[mrow];
#pragma unroll
        for (int nt = 0; nt < 4; ++nt) {
            f32x4 acc = (f32x4){0.f, 0.f, 0.f, 0.f};
            acc = __builtin_amdgcn_mfma_f32_16x16x32_bf16(xh[nt], wh0, acc, 0, 0, 0);
            acc = __builtin_amdgcn_mfma_f32_16x16x32_bf16(qh[nt], wh1, acc, 0, 0, 0);
            acc = __builtin_amdgcn_mfma_f32_16x16x32_bf16(xl[nt], wh0, acc, 0, 0, 0);
            acc = __builtin_amdgcn_mfma_f32_16x16x32_bf16(ql[nt], wh1, acc, 0, 0, 0);
            acc = __builtin_amdgcn_mfma_f32_16x16x32_bf16(xh[nt], wl0, acc, 0, 0, 0);
            acc = __builtin_amdgcn_mfma_f32_16x16x32_bf16(qh[nt], wl1, acc, 0, 0, 0);
#pragma unroll
            for (int r = 0; r < 4; ++r) rs[nt][r] += fast_exp2(acc[r] + a2);
        }
    }

    // reduce over the 16 column-lanes (same lane>>4 group holds same rows)
#pragma unroll
    for (int o = 1; o < 16; o <<= 1)
#pragma unroll
        for (int nt = 0; nt < 4; ++nt)
#pragma unroll
            for (int r = 0; r < 4; ++r) rs[nt][r] += __shfl_xor(rs[nt][r], o);

    if (r15 == 0) {
#pragma unroll
        for (int nt = 0; nt < 4; ++nt)
            *(f32x4*)(partial + (size_t)blockIdx.y * NS + n_base + nt * 16 + g * 4) = rs[nt];
    }
}

// Sum partials -> dist, block min/max -> atomics; last block finalizes out.
__global__ __launch_bounds__(256) void reduce_final(unsigned char* __restrict__ ws,
                                                    float* __restrict__ out) {
    const float* partial = (const float*)(ws + PART_OFF);
    float* dist = (float*)(ws + DIST_OFF);
    unsigned* mm = (unsigned*)(ws + MM_OFF);
    unsigned* cnt = (unsigned*)(ws + CNT_OFF);

    const int tid = threadIdx.x;
    const int n = blockIdx.x * 256 + tid;
    float v = 0.f;
#pragma unroll
    for (int j = 0; j < MSPLIT; ++j) v += partial[(size_t)j * NS + n];
    dist[n] = v;

    float mn = v, mx = v;
#pragma unroll
    for (int o = 1; o < 64; o <<= 1) {
        mn = fminf(mn, __shfl_xor(mn, o));
        mx = fmaxf(mx, __shfl_xor(mx, o));
    }
    __shared__ float smn[4], smx[4];
    __shared__ int lastFlag;
    const int wv = tid >> 6, ln = tid & 63;
    if (ln == 0) { smn[wv] = mn; smx[wv] = mx; }
    __syncthreads();
    if (tid == 0) {
#pragma unroll
        for (int j = 1; j < 4; ++j) {
            mn = fminf(mn, smn[j]);
            mx = fmaxf(mx, smx[j]);
        }
        atomicMin(mm + 0, __float_as_uint(mn));
        atomicMax(mm + 1, __float_as_uint(mx));
        __threadfence();
        unsigned old = atomicAdd(cnt, 1u);
        lastFlag = (old == (unsigned)(gridDim.x - 1));
    }
    __syncthreads();
    if (lastFlag) {
        __threadfence();
        volatile unsigned* vmm = mm;
        const float fmn = __uint_as_float(vmm[0]);
        const float fmx = __uint_as_float(vmm[1]);
        volatile float* vd = dist;
        for (int i = tid; i < NS; i += 256) out[i] = fmx + fmn - vd[i];
    }
}

extern "C" void kernel_launch(void* const* d_in, const int* in_sizes, int n_in,
                              void* d_out, int out_size, void* d_ws, size_t ws_size,
                              hipStream_t stream) {
    const float* samples = (const float*)d_in[0];
    const float* means   = (const float*)d_in[1];
    const float* stds    = (const float*)d_in[2];
    unsigned char* ws = (unsigned char*)d_ws;
    float* out = (float*)d_out;

    prep_kernel<<<dim3(8 + NS * DD / 4 / 256), 256, 0, stream>>>(samples, means, stds, ws);
    kde_mfma<<<dim3(NS / 256, MSPLIT), 256, 0, stream>>>(ws, (float*)(ws + PART_OFF));
    reduce_final<<<dim3(NS / 256), 256, 0, stream>>>(ws, out);
}

// Round 4
// 37.571 us; speedup vs baseline: 1.3872x; 1.0903x over previous
//
#include <hip/hip_runtime.h>

#define NS 8192
#define MS 2048
#define DD 32
#define MSPLIT 32

typedef __attribute__((ext_vector_type(8))) short bf16x8;
typedef __attribute__((ext_vector_type(4))) float f32x4;
typedef unsigned short u16;

// ---- ws byte offsets ----
#define WH_OFF   (0)                        // [M][64] bf16 hi  (256 KB)
#define WL_OFF   (256*1024)                 // [M][64] bf16 lo  (256 KB)
#define XH_OFF   (512*1024)                 // [N][32] s  hi    (512 KB)
#define XL_OFF   (1024*1024)                // [N][32] s  lo
#define QH_OFF   (1536*1024)                // [N][32] s^2 hi
#define QL_OFF   (2048*1024)                // [N][32] s^2 lo
#define A2_OFF   (2560*1024)                // [M] f32 (8 KB)
#define PART_OFF (A2_OFF + 8*1024)          // [MSPLIT][N] f32 (1 MB)
#define DIST_OFF (PART_OFF + MSPLIT*NS*4)   // [N] f32
#define MM_OFF   (DIST_OFF + NS*4)          // 2 u32 (min,max bits)
#define CNT_OFF  (MM_OFF + 8)               // 1 u32

__device__ inline float fast_exp2(float x) {
#if __has_builtin(__builtin_amdgcn_exp2f)
    return __builtin_amdgcn_exp2f(x);
#else
    return exp2f(x);
#endif
}

__device__ inline u16 f2bf(float x) {  // round-to-nearest-even bf16
    unsigned u = __float_as_uint(x);
    return (u16)((u + 0x7fffu + ((u >> 16) & 1u)) >> 16);
}
__device__ inline float bf2f(u16 h) { return __uint_as_float(((unsigned)h) << 16); }

// blocks 0..7: per-m coefficients W=[B;C] (hi/lo bf16, [M][64] transposed) + A2.
// blocks 8..263: per-sample split of s and s^2 into hi/lo bf16 [N][32].
__global__ __launch_bounds__(256) void prep_kernel(const float* __restrict__ samples,
                                                   const float* __restrict__ means,
                                                   const float* __restrict__ stds,
                                                   unsigned char* __restrict__ ws) {
    const int tid = threadIdx.x, bid = blockIdx.x;
    if (bid == 0 && tid == 0) {
        unsigned* mm = (unsigned*)(ws + MM_OFF);
        mm[0] = 0x7f7fffffu;  // FLT_MAX bits
        mm[1] = 0u;
        *(unsigned*)(ws + CNT_OFF) = 0u;
    }
    if (bid < 8) {
        const int m = bid * 256 + tid;
        u16* WH = (u16*)(ws + WH_OFF);
        u16* WL = (u16*)(ws + WL_OFF);
        float* A2 = (float*)(ws + A2_OFF);
        const float L2E = 1.4426950408889634f;
        float a = 0.f;
        const float4* mrow = (const float4*)(means + (size_t)m * DD);
        const float4* srow = (const float4*)(stds + (size_t)m * DD);
#pragma unroll
        for (int j = 0; j < DD / 4; ++j) {
            float4 mu4 = mrow[j];
            float4 sd4 = srow[j];
            float mu[4] = {mu4.x, mu4.y, mu4.z, mu4.w};
            float sd[4] = {sd4.x, sd4.y, sd4.z, sd4.w};
            ushort4 bh, bl, ch, cl;
            u16* pbh = (u16*)&bh; u16* pbl = (u16*)&bl;
            u16* pch = (u16*)&ch; u16* pcl = (u16*)&cl;
#pragma unroll
            for (int e = 0; e < 4; ++e) {
                float inv = 1.0f / sd[e];
                float B = L2E * mu[e] * inv;
                float C = -0.5f * L2E * inv;
                a += mu[e] * mu[e] * inv;
                u16 h = f2bf(B);
                pbh[e] = h;
                pbl[e] = f2bf(B - bf2f(h));
                h = f2bf(C);
                pch[e] = h;
                pcl[e] = f2bf(C - bf2f(h));
            }
            *(ushort4*)(WH + (size_t)m * 64 + j * 4)      = bh;
            *(ushort4*)(WH + (size_t)m * 64 + 32 + j * 4) = ch;
            *(ushort4*)(WL + (size_t)m * 64 + j * 4)      = bl;
            *(ushort4*)(WL + (size_t)m * 64 + 32 + j * 4) = cl;
        }
        A2[m] = -0.5f * L2E * a - 11.0f;  // fold mean's 1/2048 into exponent
    } else {
        const int idx = (bid - 8) * 256 + tid;  // < NS*DD/4
        float4 v = ((const float4*)samples)[idx];
        float xs[4] = {v.x, v.y, v.z, v.w};
        ushort4 hx, lx, hq, lq;
        u16* ph = (u16*)&hx; u16* pl = (u16*)&lx;
        u16* qh = (u16*)&hq; u16* ql = (u16*)&lq;
#pragma unroll
        for (int j = 0; j < 4; ++j) {
            float x = xs[j];
            u16 h = f2bf(x);
            ph[j] = h;
            pl[j] = f2bf(x - bf2f(h));
            float q = x * x;
            u16 hh = f2bf(q);
            qh[j] = hh;
            ql[j] = f2bf(q - bf2f(hh));
        }
        *(ushort4*)((u16*)(ws + XH_OFF) + idx * 4) = hx;
        *(ushort4*)((u16*)(ws + XL_OFF) + idx * 4) = lx;
        *(ushort4*)((u16*)(ws + QH_OFF) + idx * 4) = hq;
        *(ushort4*)((u16*)(ws + QL_OFF) + idx * 4) = lq;
    }
}

// Each wave: 64 rows (4 n-tiles) x 64 m (4 m-tiles). 6 MFMA per 16x16 tile
// (Xh*Wh, Xh*Wl, Xl*Wh over 2 k-steps). Epilogue: exp2(acc + A2[m]) row-summed.
// unroll 2 on the it loop + min 3 waves/EU: keeps live VGPRs ~145 < 168 budget
// (full unroll + ",4" in round 3 forced a spill: 185 live > 128 cap).
__global__ __launch_bounds__(256, 3) void kde_mfma(const unsigned char* __restrict__ ws,
                                                   float* __restrict__ partial) {
    const u16* XH = (const u16*)(ws + XH_OFF);
    const u16* XL = (const u16*)(ws + XL_OFF);
    const u16* QH = (const u16*)(ws + QH_OFF);
    const u16* QL = (const u16*)(ws + QL_OFF);
    const u16* WH = (const u16*)(ws + WH_OFF);
    const u16* WL = (const u16*)(ws + WL_OFF);
    const float* A2 = (const float*)(ws + A2_OFF);

    const int lane = threadIdx.x & 63, wid = threadIdx.x >> 6;
    const int r15 = lane & 15, g = lane >> 4;
    const int n_base = (blockIdx.x * 4 + wid) * 64;

    bf16x8 xh[4], xl[4], qh[4], ql[4];
#pragma unroll
    for (int nt = 0; nt < 4; ++nt) {
        const size_t off = (size_t)(n_base + nt * 16 + r15) * DD + g * 8;
        xh[nt] = *(const bf16x8*)(XH + off);
        xl[nt] = *(const bf16x8*)(XL + off);
        qh[nt] = *(const bf16x8*)(QH + off);
        ql[nt] = *(const bf16x8*)(QL + off);
    }

    f32x4 rs[4];
#pragma unroll
    for (int nt = 0; nt < 4; ++nt) rs[nt] = (f32x4){0.f, 0.f, 0.f, 0.f};

    const int m0 = blockIdx.y * 64;
#pragma unroll 2
    for (int it = 0; it < 4; ++it) {
        const int mrow = m0 + it * 16 + r15;
        const size_t woff = (size_t)mrow * 64 + g * 8;
        bf16x8 wh0 = *(const bf16x8*)(WH + woff);
        bf16x8 wh1 = *(const bf16x8*)(WH + woff + 32);
        bf16x8 wl0 = *(const bf16x8*)(WL + woff);
        bf16x8 wl1 = *(const bf16x8*)(WL + woff + 32);
        const float a2 = A2[mrow];
#pragma unroll
        for (int nt = 0; nt < 4; ++nt) {
            f32x4 acc = (f32x4){0.f, 0.f, 0.f, 0.f};
            acc = __builtin_amdgcn_mfma_f32_16x16x32_bf16(xh[nt], wh0, acc, 0, 0, 0);
            acc = __builtin_amdgcn_mfma_f32_16x16x32_bf16(qh[nt], wh1, acc, 0, 0, 0);
            acc = __builtin_amdgcn_mfma_f32_16x16x32_bf16(xl[nt], wh0, acc, 0, 0, 0);
            acc = __builtin_amdgcn_mfma_f32_16x16x32_bf16(ql[nt], wh1, acc, 0, 0, 0);
            acc = __builtin_amdgcn_mfma_f32_16x16x32_bf16(xh[nt], wl0, acc, 0, 0, 0);
            acc = __builtin_amdgcn_mfma_f32_16x16x32_bf16(qh[nt], wl1, acc, 0, 0, 0);
#pragma unroll
            for (int r = 0; r < 4; ++r) rs[nt][r] += fast_exp2(acc[r] + a2);
        }
    }

    // reduce over the 16 column-lanes (same lane>>4 group holds same rows)
#pragma unroll
    for (int o = 1; o < 16; o <<= 1)
#pragma unroll
        for (int nt = 0; nt < 4; ++nt)
#pragma unroll
            for (int r = 0; r < 4; ++r) rs[nt][r] += __shfl_xor(rs[nt][r], o);

    if (r15 == 0) {
#pragma unroll
        for (int nt = 0; nt < 4; ++nt)
            *(f32x4*)(partial + (size_t)blockIdx.y * NS + n_base + nt * 16 + g * 4) = rs[nt];
    }
}

// Sum partials -> dist, block min/max -> atomics; last block finalizes out.
__global__ __launch_bounds__(256) void reduce_final(unsigned char* __restrict__ ws,
                                                    float* __restrict__ out) {
    const float* partial = (const float*)(ws + PART_OFF);
    float* dist = (float*)(ws + DIST_OFF);
    unsigned* mm = (unsigned*)(ws + MM_OFF);
    unsigned* cnt = (unsigned*)(ws + CNT_OFF);

    const int tid = threadIdx.x;
    const int n = blockIdx.x * 256 + tid;
    float v = 0.f;
#pragma unroll
    for (int j = 0; j < MSPLIT; ++j) v += partial[(size_t)j * NS + n];
    dist[n] = v;

    float mn = v, mx = v;
#pragma unroll
    for (int o = 1; o < 64; o <<= 1) {
        mn = fminf(mn, __shfl_xor(mn, o));
        mx = fmaxf(mx, __shfl_xor(mx, o));
    }
    __shared__ float smn[4], smx[4];
    __shared__ int lastFlag;
    const int wv = tid >> 6, ln = tid & 63;
    if (ln == 0) { smn[wv] = mn; smx[wv] = mx; }
    __syncthreads();
    if (tid == 0) {
#pragma unroll
        for (int j = 1; j < 4; ++j) {
            mn = fminf(mn, smn[j]);
            mx = fmaxf(mx, smx[j]);
        }
        atomicMin(mm + 0, __float_as_uint(mn));
        atomicMax(mm + 1, __float_as_uint(mx));
        __threadfence();
        unsigned old = atomicAdd(cnt, 1u);
        lastFlag = (old == (unsigned)(gridDim.x - 1));
    }
    __syncthreads();
    if (lastFlag) {
        __threadfence();
        volatile unsigned* vmm = mm;
        const float fmn = __uint_as_float(vmm[0]);
        const float fmx = __uint_as_float(vmm[1]);
        volatile float* vd = dist;
        for (int i = tid; i < NS; i += 256) out[i] = fmx + fmn - vd[i];
    }
}

extern "C" void kernel_launch(void* const* d_in, const int* in_sizes, int n_in,
                              void* d_out, int out_size, void* d_ws, size_t ws_size,
                              hipStream_t stream) {
    const float* samples = (const float*)d_in[0];
    const float* means   = (const float*)d_in[1];
    const float* stds    = (const float*)d_in[2];
    unsigned char* ws = (unsigned char*)d_ws;
    float* out = (float*)d_out;

    prep_kernel<<<dim3(8 + NS * DD / 4 / 256), 256, 0, stream>>>(samples, means, stds, ws);
    kde_mfma<<<dim3(NS / 256, MSPLIT), 256, 0, stream>>>(ws, (float*)(ws + PART_OFF));
    reduce_final<<<dim3(NS / 256), 256, 0, stream>>>(ws, out);
}

// Round 5
// 36.119 us; speedup vs baseline: 1.4429x; 1.0402x over previous
//
#include <hip/hip_runtime.h>

#define NS 8192
#define MS 2048
#define DD 32
#define MSPLIT 32

typedef __attribute__((ext_vector_type(8))) short bf16x8;
typedef __attribute__((ext_vector_type(4))) float f32x4;
typedef unsigned short u16;

// ---- ws byte offsets ----
#define WH_OFF   (0)                        // [M][64] bf16 hi  (256 KB)
#define WL_OFF   (256*1024)                 // [M][64] bf16 lo  (256 KB)
#define XH_OFF   (512*1024)                 // [N][32] s  hi    (512 KB)
#define XL_OFF   (1024*1024)                // [N][32] s  lo
#define QH_OFF   (1536*1024)                // [N][32] s^2 hi
#define QL_OFF   (2048*1024)                // [N][32] s^2 lo
#define A2_OFF   (2560*1024)                // [M] f32 (8 KB)
#define PART_OFF (A2_OFF + 8*1024)          // [MSPLIT][N] f32 (1 MB)
#define DIST_OFF (PART_OFF + MSPLIT*NS*4)   // [N] f32
#define MM_OFF   (DIST_OFF + NS*4)          // 2 u32 (min,max bits)
#define CNT_OFF  (MM_OFF + 8)               // 1 u32

__device__ inline float fast_exp2(float x) {
#if __has_builtin(__builtin_amdgcn_exp2f)
    return __builtin_amdgcn_exp2f(x);
#else
    return exp2f(x);
#endif
}

__device__ inline u16 f2bf(float x) {  // round-to-nearest-even bf16
    unsigned u = __float_as_uint(x);
    return (u16)((u + 0x7fffu + ((u >> 16) & 1u)) >> 16);
}
__device__ inline float bf2f(u16 h) { return __uint_as_float(((unsigned)h) << 16); }

// prep, rebalanced:
//   blocks 0..63   : W path — one thread per (m, 8-wide k chunk). 16384 threads,
//                    float4 loads, COALESCED ushort4 stores (round-4 version ran
//                    this on 8 blocks with 128B-stride scattered stores = straggler).
//                    A2[m] via shfl_xor reduce within each 8-lane group.
//   blocks 64..319 : X path — split s, s^2 into bf16 hi/lo, [N][32], coalesced.
__global__ __launch_bounds__(256) void prep_kernel(const float* __restrict__ samples,
                                                   const float* __restrict__ means,
                                                   const float* __restrict__ stds,
                                                   unsigned char* __restrict__ ws) {
    const int tid = threadIdx.x, bid = blockIdx.x;
    if (bid == 0 && tid == 0) {
        unsigned* mm = (unsigned*)(ws + MM_OFF);
        mm[0] = 0x7f7fffffu;  // FLT_MAX bits
        mm[1] = 0u;
        *(unsigned*)(ws + CNT_OFF) = 0u;
    }
    if (bid < 64) {
        const int p = bid * 256 + tid;        // < 16384
        const int m = p >> 3;                 // mean index
        const int c = p & 7;                  // k-chunk: c<4 -> B rows, c>=4 -> C rows
        const int d0 = (c & 3) * 8;           // source d range
        const bool isB = (c < 4);

        const float4* mrow = (const float4*)(means + (size_t)m * DD + d0);
        const float4* srow = (const float4*)(stds  + (size_t)m * DD + d0);
        float4 mu4a = mrow[0], mu4b = mrow[1];
        float4 sd4a = srow[0], sd4b = srow[1];
        float mu[8] = {mu4a.x, mu4a.y, mu4a.z, mu4a.w, mu4b.x, mu4b.y, mu4b.z, mu4b.w};
        float sd[8] = {sd4a.x, sd4a.y, sd4a.z, sd4a.w, sd4b.x, sd4b.y, sd4b.z, sd4b.w};

        const float L2E = 1.4426950408889634f;
        float a = 0.f;
        ushort4 h0, h1, l0, l1;
        u16* ph = (u16*)&h0;  // h0,h1 contiguous? not guaranteed; index separately
        u16* ph1 = (u16*)&h1;
        u16* pl = (u16*)&l0;
        u16* pl1 = (u16*)&l1;
#pragma unroll
        for (int e = 0; e < 8; ++e) {
            float inv = 1.0f / sd[e];
            float val = isB ? (L2E * mu[e] * inv) : (-0.5f * L2E * inv);
            if (isB) a += mu[e] * mu[e] * inv;
            u16 h = f2bf(val);
            u16 l = f2bf(val - bf2f(h));
            if (e < 4) { ph[e] = h; pl[e] = l; }
            else       { ph1[e - 4] = h; pl1[e - 4] = l; }
        }
        // reduce a over the 8-lane group (only c<4 lanes contribute, others add 0)
        a += __shfl_xor(a, 1);
        a += __shfl_xor(a, 2);
        a += __shfl_xor(a, 4);
        if (c == 0) ((float*)(ws + A2_OFF))[m] = -0.5f * L2E * a - 11.0f;

        u16* WH = (u16*)(ws + WH_OFF) + (size_t)m * 64 + c * 8;
        u16* WL = (u16*)(ws + WL_OFF) + (size_t)m * 64 + c * 8;
        *(ushort4*)(WH)     = h0;
        *(ushort4*)(WH + 4) = h1;
        *(ushort4*)(WL)     = l0;
        *(ushort4*)(WL + 4) = l1;
    } else {
        const int idx = (bid - 64) * 256 + tid;  // < NS*DD/4 = 65536
        float4 v = ((const float4*)samples)[idx];
        float xs[4] = {v.x, v.y, v.z, v.w};
        ushort4 hx, lx, hq, lq;
        u16* ph = (u16*)&hx; u16* pl = (u16*)&lx;
        u16* qh = (u16*)&hq; u16* ql = (u16*)&lq;
#pragma unroll
        for (int j = 0; j < 4; ++j) {
            float x = xs[j];
            u16 h = f2bf(x);
            ph[j] = h;
            pl[j] = f2bf(x - bf2f(h));
            float q = x * x;
            u16 hh = f2bf(q);
            qh[j] = hh;
            ql[j] = f2bf(q - bf2f(hh));
        }
        *(ushort4*)((u16*)(ws + XH_OFF) + idx * 4) = hx;
        *(ushort4*)((u16*)(ws + XL_OFF) + idx * 4) = lx;
        *(ushort4*)((u16*)(ws + QH_OFF) + idx * 4) = hq;
        *(ushort4*)((u16*)(ws + QL_OFF) + idx * 4) = lq;
    }
}

// Each wave: 64 rows (4 n-tiles) x 64 m (4 m-tiles). 6 MFMA per 16x16 tile
// (Xh*Wh, Xh*Wl, Xl*Wh over 2 k-steps). Epilogue: exp2(acc + A2[m]) row-summed.
// unroll 2 + min 3 waves/EU keeps live VGPRs under the ~170 budget (no spill).
__global__ __launch_bounds__(256, 3) void kde_mfma(const unsigned char* __restrict__ ws,
                                                   float* __restrict__ partial) {
    const u16* XH = (const u16*)(ws + XH_OFF);
    const u16* XL = (const u16*)(ws + XL_OFF);
    const u16* QH = (const u16*)(ws + QH_OFF);
    const u16* QL = (const u16*)(ws + QL_OFF);
    const u16* WH = (const u16*)(ws + WH_OFF);
    const u16* WL = (const u16*)(ws + WL_OFF);
    const float* A2 = (const float*)(ws + A2_OFF);

    const int lane = threadIdx.x & 63, wid = threadIdx.x >> 6;
    const int r15 = lane & 15, g = lane >> 4;
    const int n_base = (blockIdx.x * 4 + wid) * 64;

    bf16x8 xh[4], xl[4], qh[4], ql[4];
#pragma unroll
    for (int nt = 0; nt < 4; ++nt) {
        const size_t off = (size_t)(n_base + nt * 16 + r15) * DD + g * 8;
        xh[nt] = *(const bf16x8*)(XH + off);
        xl[nt] = *(const bf16x8*)(XL + off);
        qh[nt] = *(const bf16x8*)(QH + off);
        ql[nt] = *(const bf16x8*)(QL + off);
    }

    f32x4 rs[4];
#pragma unroll
    for (int nt = 0; nt < 4; ++nt) rs[nt] = (f32x4){0.f, 0.f, 0.f, 0.f};

    const int m0 = blockIdx.y * 64;
#pragma unroll 2
    for (int it = 0; it < 4; ++it) {
        const int mrow = m0 + it * 16 + r15;
        const size_t woff = (size_t)mrow * 64 + g * 8;
        bf16x8 wh0 = *(const bf16x8*)(WH + woff);
        bf16x8 wh1 = *(const bf16x8*)(WH + woff + 32);
        bf16x8 wl0 = *(const bf16x8*)(WL + woff);
        bf16x8 wl1 = *(const bf16x8*)(WL + woff + 32);
        const float a2 = A2[mrow];
#pragma unroll
        for (int nt = 0; nt < 4; ++nt) {
            f32x4 acc = (f32x4){0.f, 0.f, 0.f, 0.f};
            acc = __builtin_amdgcn_mfma_f32_16x16x32_bf16(xh[nt], wh0, acc, 0, 0, 0);
            acc = __builtin_amdgcn_mfma_f32_16x16x32_bf16(qh[nt], wh1, acc, 0, 0, 0);
            acc = __builtin_amdgcn_mfma_f32_16x16x32_bf16(xl[nt], wh0, acc, 0, 0, 0);
            acc = __builtin_amdgcn_mfma_f32_16x16x32_bf16(ql[nt], wh1, acc, 0, 0, 0);
            acc = __builtin_amdgcn_mfma_f32_16x16x32_bf16(xh[nt], wl0, acc, 0, 0, 0);
            acc = __builtin_amdgcn_mfma_f32_16x16x32_bf16(qh[nt], wl1, acc, 0, 0, 0);
#pragma unroll
            for (int r = 0; r < 4; ++r) rs[nt][r] += fast_exp2(acc[r] + a2);
        }
    }

    // reduce over the 16 column-lanes (same lane>>4 group holds same rows)
#pragma unroll
    for (int o = 1; o < 16; o <<= 1)
#pragma unroll
        for (int nt = 0; nt < 4; ++nt)
#pragma unroll
            for (int r = 0; r < 4; ++r) rs[nt][r] += __shfl_xor(rs[nt][r], o);

    if (r15 == 0) {
#pragma unroll
        for (int nt = 0; nt < 4; ++nt)
            *(f32x4*)(partial + (size_t)blockIdx.y * NS + n_base + nt * 16 + g * 4) = rs[nt];
    }
}

// Sum partials -> dist, block min/max -> atomics; last block finalizes out.
__global__ __launch_bounds__(256) void reduce_final(unsigned char* __restrict__ ws,
                                                    float* __restrict__ out) {
    const float* partial = (const float*)(ws + PART_OFF);
    float* dist = (float*)(ws + DIST_OFF);
    unsigned* mm = (unsigned*)(ws + MM_OFF);
    unsigned* cnt = (unsigned*)(ws + CNT_OFF);

    const int tid = threadIdx.x;
    const int n = blockIdx.x * 256 + tid;
    float v = 0.f;
#pragma unroll
    for (int j = 0; j < MSPLIT; ++j) v += partial[(size_t)j * NS + n];
    dist[n] = v;

    float mn = v, mx = v;
#pragma unroll
    for (int o = 1; o < 64; o <<= 1) {
        mn = fminf(mn, __shfl_xor(mn, o));
        mx = fmaxf(mx, __shfl_xor(mx, o));
    }
    __shared__ float smn[4], smx[4];
    __shared__ int lastFlag;
    const int wv = tid >> 6, ln = tid & 63;
    if (ln == 0) { smn[wv] = mn; smx[wv] = mx; }
    __syncthreads();
    if (tid == 0) {
#pragma unroll
        for (int j = 1; j < 4; ++j) {
            mn = fminf(mn, smn[j]);
            mx = fmaxf(mx, smx[j]);
        }
        atomicMin(mm + 0, __float_as_uint(mn));
        atomicMax(mm + 1, __float_as_uint(mx));
        __threadfence();
        unsigned old = atomicAdd(cnt, 1u);
        lastFlag = (old == (unsigned)(gridDim.x - 1));
    }
    __syncthreads();
    if (lastFlag) {
        __threadfence();
        volatile unsigned* vmm = mm;
        const float fmn = __uint_as_float(vmm[0]);
        const float fmx = __uint_as_float(vmm[1]);
        volatile float* vd = dist;
        for (int i = tid; i < NS; i += 256) out[i] = fmx + fmn - vd[i];
    }
}

extern "C" void kernel_launch(void* const* d_in, const int* in_sizes, int n_in,
                              void* d_out, int out_size, void* d_ws, size_t ws_size,
                              hipStream_t stream) {
    const float* samples = (const float*)d_in[0];
    const float* means   = (const float*)d_in[1];
    const float* stds    = (const float*)d_in[2];
    unsigned char* ws = (unsigned char*)d_ws;
    float* out = (float*)d_out;

    prep_kernel<<<dim3(64 + NS * DD / 4 / 256), 256, 0, stream>>>(samples, means, stds, ws);
    kde_mfma<<<dim3(NS / 256, MSPLIT), 256, 0, stream>>>(ws, (float*)(ws + PART_OFF));
    reduce_final<<<dim3(NS / 256), 256, 0, stream>>>(ws, out);
}